// Round 7
// baseline (235.788 us; speedup 1.0000x reference)
//
#include <hip/hip_runtime.h>
#include <hip/hip_bf16.h>

#define DEV __device__ __forceinline__

typedef __bf16 bf16x8 __attribute__((ext_vector_type(8)));
typedef float  f32x4  __attribute__((ext_vector_type(4)));
typedef unsigned short u16;

static constexpr float LOG2E = 1.44269504088896340736f;

// fp32 -> bf16 round-to-nearest-even (scalar)
DEV u16 f2bf(float f) {
    unsigned u = __float_as_uint(f);
    u += 0x7fffu + ((u >> 16) & 1u);
    return (u16)(u >> 16);
}

// pack 2 fp32 -> 2 bf16 in one v_perm (round-half-up)
DEV unsigned pack_rn(float a, float b) {
    unsigned ua = __float_as_uint(a) + 0x8000u;
    unsigned ub = __float_as_uint(b) + 0x8000u;
    return __builtin_amdgcn_perm(ub, ua, 0x07060302u);  // [ub.hi16 : ua.hi16]
}

typedef const __attribute__((address_space(1))) void* gas_ptr;
typedef __attribute__((address_space(3))) void* las_ptr;

// async global->LDS, 16B per lane. LDS dest = wave-uniform base + lane*16.
DEV void async16(const void* g, void* l) {
    __builtin_amdgcn_global_load_lds((gas_ptr)g, (las_ptr)l, 16, 0, 0);
}

// ---------------- convert fp32 -> bf16 (7 tensors via blockIdx.z) -------------
__global__ __launch_bounds__(256)
void convert_all(const float* q, const float* k, const float* v,
                 const float* wq, const float* wk, const float* wv, const float* wo,
                 u16* oq, u16* ok, u16* ov, u16* owq, u16* owk, u16* owv, u16* owo)
{
    const float* src; u16* dst; int n;
    switch (blockIdx.z) {
        case 0: src = q;  dst = oq;  n = 4194304; break;
        case 1: src = k;  dst = ok;  n = 4194304; break;
        case 2: src = v;  dst = ov;  n = 4194304; break;
        case 3: src = wq; dst = owq; n = 1048576; break;
        case 4: src = wk; dst = owk; n = 1048576; break;
        case 5: src = wv; dst = owv; n = 1048576; break;
        default: src = wo; dst = owo; n = 1048576; break;
    }
    int n4 = n >> 2;
    int stride = gridDim.x * blockDim.x;
    for (int i = blockIdx.x * blockDim.x + threadIdx.x; i < n4; i += stride) {
        float4 f = ((const float4*)src)[i];
        uint2 o;
        o.x = pack_rn(f.x, f.y);
        o.y = pack_rn(f.z, f.w);
        ((uint2*)dst)[i] = o;
    }
}

// ------------- 128x128 bf16 GEMM core: C = A[rows,1024] @ B[rows,1024]^T ------
// 256 threads = 4 waves in 2x2; each wave computes 64x64 (4x4 mfma tiles).
// LDS tiles XOR-swizzled (16B chunk ^= row&7) -> conflict-floor b128 reads.
DEV void gemm128_core(const u16* __restrict__ A, const u16* __restrict__ B,
                      int rowBase, int colBase,
                      u16* As, u16* Bs, f32x4 acc[4][4])
{
    const int tid = threadIdx.x;
    const int w = tid >> 6, l = tid & 63;
    const int lr = l & 15, lq = l >> 4;
    const int srow = l >> 3, swcol = ((l & 7) ^ (l >> 3)) * 8;
    const int wr0 = (w >> 1) * 64, wc0 = (w & 1) * 64;
    const int sx = lr & 7;

#pragma unroll
    for (int i = 0; i < 4; ++i)
#pragma unroll
        for (int j = 0; j < 4; ++j) acc[i][j] = (f32x4){0.f, 0.f, 0.f, 0.f};

    for (int k0 = 0; k0 < 1024; k0 += 64) {
        __syncthreads();   // previous iter's LDS reads done
#pragma unroll
        for (int c = 0; c < 4; ++c) {
            const int ci = c * 4 + w;            // 1KB chunk = 8 rows of 128B
            const int row = ci * 8 + srow;
            async16(&A[(size_t)(rowBase + row) * 1024 + k0 + swcol], &As[ci * 512]);
            async16(&B[(size_t)(colBase + row) * 1024 + k0 + swcol], &Bs[ci * 512]);
        }
        __syncthreads();   // vmcnt(0) drain makes staging visible
#pragma unroll
        for (int ks = 0; ks < 2; ++ks) {
            bf16x8 a[4], b[4];
#pragma unroll
            for (int i = 0; i < 4; ++i)
                a[i] = *(const bf16x8*)&As[(wr0 + i * 16 + lr) * 64 + (((ks * 4 + lq) ^ sx) * 8)];
#pragma unroll
            for (int j = 0; j < 4; ++j)
                b[j] = *(const bf16x8*)&Bs[(wc0 + j * 16 + lr) * 64 + (((ks * 4 + lq) ^ sx) * 8)];
#pragma unroll
            for (int i = 0; i < 4; ++i)
#pragma unroll
                for (int j = 0; j < 4; ++j)
                    acc[i][j] = __builtin_amdgcn_mfma_f32_16x16x32_bf16(a[i], b[j], acc[i][j], 0, 0, 0);
        }
    }
}

// --------- QKV projection: X[4096,1024] @ W^T -> [B,H,S,D] bf16 ---------------
// Q output (z==0) pre-scaled by LOG2E so attention softmax is a raw exp2.
__global__ __launch_bounds__(256, 4)
void proj_gemm(const u16* __restrict__ Xq, const u16* __restrict__ Xk, const u16* __restrict__ Xv,
               const u16* __restrict__ Wq, const u16* __restrict__ Wk, const u16* __restrict__ Wv,
               u16* __restrict__ Qo, u16* __restrict__ Ko, u16* __restrict__ Vo)
{
    __shared__ __align__(16) u16 As[128 * 64];
    __shared__ __align__(16) u16 Bs[128 * 64];
    const u16* A; const u16* W; u16* C; float scale;
    if (blockIdx.z == 0)      { A = Xq; W = Wq; C = Qo; scale = LOG2E; }
    else if (blockIdx.z == 1) { A = Xk; W = Wk; C = Ko; scale = 1.0f; }
    else                      { A = Xv; W = Wv; C = Vo; scale = 1.0f; }

    f32x4 acc[4][4];
    gemm128_core(A, W, blockIdx.y * 128, blockIdx.x * 128, As, Bs, acc);

    const int tid = threadIdx.x, w = tid >> 6, l = tid & 63;
    const int lr = l & 15, lq = l >> 4;
    const int r0 = blockIdx.y * 128 + (w >> 1) * 64;
    const int c0 = blockIdx.x * 128 + (w & 1) * 64;
#pragma unroll
    for (int i = 0; i < 4; ++i)
#pragma unroll
        for (int j = 0; j < 4; ++j)
#pragma unroll
            for (int r = 0; r < 4; ++r) {
                int row = r0 + i * 16 + lq * 4 + r;   // X row = s*2 + b
                int col = c0 + j * 16 + lr;           // n = h*64 + d
                int s = row >> 1, b = row & 1, h = col >> 6, d = col & 63;
                C[(size_t)((b * 16 + h) * 2048 + s) * 64 + d] = f2bf(acc[i][j][r] * scale);
            }
}

// --------- V transpose: [B,H,S,D] -> [B,H,D,S] bf16 ---------------------------
__global__ __launch_bounds__(256)
void transpose_v(const u16* __restrict__ Vin, u16* __restrict__ Vout)
{
    __shared__ u16 T[64][72];
    const int bh = blockIdx.y;
    const int s0 = blockIdx.x * 64;
    const int t = threadIdx.x;
    const size_t base = (size_t)bh * 2048 * 64;
    const int row = t >> 3, cc = (t & 7) * 8;
#pragma unroll
    for (int i = 0; i < 2; ++i) {
        int r = i * 32 + row;
        uint4 v = *(const uint4*)&Vin[base + (size_t)(s0 + r) * 64 + cc];
        u16* p = (u16*)&v;
#pragma unroll
        for (int j = 0; j < 8; ++j) T[r][cc + j] = p[j];
    }
    __syncthreads();
#pragma unroll
    for (int i = 0; i < 2; ++i) {
        int d = i * 32 + row;
        alignas(16) u16 tmp[8];
#pragma unroll
        for (int j = 0; j < 8; ++j) tmp[j] = T[cc + j][d];
        *(uint4*)&Vout[base + (size_t)d * 2048 + s0 + cc] = *(const uint4*)tmp;
    }
}

// --------- flash attention v7: 128-thr blocks, 32q/wave, K-tile 32 -------------
// Theory: v6 was LDS-BW bound (~49 TB/s of the 69 ceiling). 32q/wave register
// blocking (qt=2) amortizes K/V fragment reads over 2x MFMA; K-tile 32 makes
// PV contraction exactly one mfma K-step. Per-wave-iter LDS: 10 b128 reads
// (ak4+av4+bp2) + 4KB staging + 2KB P = 16KB per (32q x 32k) vs v6 24KB per
// (16q x 64k) -> total 2.1GB vs 3.1GB. Grid 1024 x 128thr, 21KB LDS -> 7 blk/CU.
__global__ __launch_bounds__(128, 4)
void attn_kernel(const u16* __restrict__ Qg, const u16* __restrict__ Kg,
                 const u16* __restrict__ Vtg, u16* __restrict__ attn)
{
    // KV buf: [K tile 32x64 = 2048 elems][V tile 64x32 = 2048 elems] = 8KB each
    __shared__ __align__(16) u16 KV[2][4096];
    __shared__ __align__(16) u16 Ps[2 * 32 * 40];   // per-wave P[32 q][40] (k 0..32 + pad)

    const int tid = threadIdx.x, w = tid >> 6, l = tid & 63;
    const int lr = l & 15, lq = l >> 4;
    const int sx = lr & 7;
    // XCD-aware remap: xcd = lin&7; 4 bh per xcd, 32 q-blocks per bh
    const int lin = blockIdx.x + (blockIdx.y << 5);   // gridDim.x == 32
    const int grp = lin >> 3;                          // [0,128)
    const int bh = (lin & 7) * 4 + (grp >> 5);
    const int q0 = (grp & 31) * 64;
    const size_t base = (size_t)bh * 2048 * 64;
    // staging lane maps
    const int srow8 = l >> 3, swcol = ((l & 7) ^ (l >> 3)) * 8;          // 128B rows (K,Q)
    const int vrow = l >> 2, vcol = ((l & 3) ^ ((l >> 3) & 3)) * 8;      // 64B rows (V)
    u16* Pw = &Ps[w * 1280];                           // this wave's P [32][40]

    // stage Q tile (64x64 = 8KB) into KV[1]; K0 (32x64) + V0 (64x32) into KV[0]
#pragma unroll
    for (int c = 0; c < 4; ++c) {
        int ci = w * 4 + c;
        async16(&Qg[base + (size_t)(q0 + ci * 8 + srow8) * 64 + swcol], &KV[1][ci * 512]);
    }
#pragma unroll
    for (int c = 0; c < 2; ++c) {
        int ci = w * 2 + c;
        async16(&Kg[base + (size_t)(ci * 8 + srow8) * 64 + swcol], &KV[0][ci * 512]);
        async16(&Vtg[base + (size_t)(ci * 16 + vrow) * 2048 + vcol], &KV[0][2048 + ci * 512]);
    }
    __syncthreads();   // staging visible

    // hoist Q fragments: wave w owns q rows [w*32, w*32+32), qt subtiles of 16
    bf16x8 bq[2][2];
#pragma unroll
    for (int qt = 0; qt < 2; ++qt)
#pragma unroll
        for (int ks = 0; ks < 2; ++ks)
            bq[qt][ks] = *(const bf16x8*)&KV[1][(w * 32 + qt * 16 + lr) * 64 + (((ks * 4 + lq) ^ sx) * 8)];
    __syncthreads();   // all waves done reading Q before KV[1] is overwritten

    f32x4 O[2][4];     // O^T per qt: [d-tile dmt][q=lr]; d = dmt*16+lq*4+r
    float l_i[2] = {0.f, 0.f};
#pragma unroll
    for (int qt = 0; qt < 2; ++qt)
#pragma unroll
        for (int mt = 0; mt < 4; ++mt) O[qt][mt] = (f32x4){0.f, 0.f, 0.f, 0.f};

    for (int kt = 0; kt < 64; ++kt) {
        const int cur = kt & 1;
        const u16* Ks = &KV[cur][0];
        const u16* Vs = &KV[cur][2048];
        // prefetch next K/V tile into the alternate buffer (overlaps compute)
        if (kt < 63) {
#pragma unroll
            for (int c = 0; c < 2; ++c) {
                int ci = w * 2 + c;
                async16(&Kg[base + (size_t)((kt + 1) * 32 + ci * 8 + srow8) * 64 + swcol],
                        &KV[cur ^ 1][ci * 512]);
                async16(&Vtg[base + (size_t)(ci * 16 + vrow) * 2048 + (kt + 1) * 32 + vcol],
                        &KV[cur ^ 1][2048 + ci * 512]);
            }
        }

        // S^T = K_tile * Q_tile^T : D[m=k-local][n=q]; per qt: k = mt*16+lq*4+r
        f32x4 S[2][2];
        {
            bf16x8 ak[2][2];
#pragma unroll
            for (int mt = 0; mt < 2; ++mt)
#pragma unroll
                for (int ks = 0; ks < 2; ++ks)
                    ak[mt][ks] = *(const bf16x8*)&Ks[(mt * 16 + lr) * 64 + (((ks * 4 + lq) ^ sx) * 8)];
#pragma unroll
            for (int qt = 0; qt < 2; ++qt)
#pragma unroll
                for (int mt = 0; mt < 2; ++mt) {
                    S[qt][mt] = __builtin_amdgcn_mfma_f32_16x16x32_bf16(ak[mt][0], bq[qt][0],
                                    (f32x4){0.f, 0.f, 0.f, 0.f}, 0, 0, 0);
                    S[qt][mt] = __builtin_amdgcn_mfma_f32_16x16x32_bf16(ak[mt][1], bq[qt][1],
                                    S[qt][mt], 0, 0, 0);
                }
        }

        // softmax (no max; Q pre-scaled by LOG2E) + P -> LDS (stride-40 rows)
#pragma unroll
        for (int qt = 0; qt < 2; ++qt) {
            float rs = 0.f;
#pragma unroll
            for (int mt = 0; mt < 2; ++mt)
#pragma unroll
                for (int r = 0; r < 4; ++r) {
                    float p = __builtin_amdgcn_exp2f(S[qt][mt][r]);
                    S[qt][mt][r] = p;
                    rs += p;
                }
            rs += __shfl_xor(rs, 16, 64);
            rs += __shfl_xor(rs, 32, 64);
            l_i[qt] += rs;
            // P[q = qt*16+lr][k = mt*16+lq*4 .. +4] b64 write; banks <=2-way
#pragma unroll
            for (int mt = 0; mt < 2; ++mt) {
                uint2 pk;
                pk.x = pack_rn(S[qt][mt][0], S[qt][mt][1]);
                pk.y = pack_rn(S[qt][mt][2], S[qt][mt][3]);
                *(uint2*)&Pw[(qt * 16 + lr) * 40 + mt * 16 + lq * 4] = pk;
            }
        }
        // same-wave LDS write->read: wave-ordered, no barrier needed

        // O^T += V^T * P^T : one mfma K-step (k-tile = 32)
        {
            bf16x8 av[4], bp[2];
#pragma unroll
            for (int qt = 0; qt < 2; ++qt)
                bp[qt] = *(const bf16x8*)&Pw[(qt * 16 + lr) * 40 + lq * 8];
#pragma unroll
            for (int mt = 0; mt < 4; ++mt)
                av[mt] = *(const bf16x8*)&Vs[mt * 512 + lr * 32 + ((lq ^ ((lr >> 1) & 3)) * 8)];
#pragma unroll
            for (int qt = 0; qt < 2; ++qt)
#pragma unroll
                for (int mt = 0; mt < 4; ++mt)
                    O[qt][mt] = __builtin_amdgcn_mfma_f32_16x16x32_bf16(av[mt], bp[qt], O[qt][mt], 0, 0, 0);
        }

        __syncthreads();   // next-tile staging done; everyone done reading cur
    }

    // epilogue: lane holds q = qt*16+lr -> s = q0 + w*32 + qt*16 + lr
    const int b = bh >> 4, h = bh & 15;
#pragma unroll
    for (int qt = 0; qt < 2; ++qt) {
        const int s = q0 + w * 32 + qt * 16 + lr;
        const float inv = 1.f / l_i[qt];
        u16* orow = &attn[(size_t)(s * 2 + b) * 1024 + h * 64];
#pragma unroll
        for (int mt = 0; mt < 4; ++mt) {
            uint2 pk;
            pk.x = pack_rn(O[qt][mt][0] * inv, O[qt][mt][1] * inv);
            pk.y = pack_rn(O[qt][mt][2] * inv, O[qt][mt][3] * inv);
            *(uint2*)&orow[mt * 16 + lq * 4] = pk;
        }
    }
}

// --------- output projection: attn[4096,1024] @ Wo^T -> fp32 out --------------
__global__ __launch_bounds__(256, 4)
void out_gemm(const u16* __restrict__ A, const u16* __restrict__ W, float* __restrict__ out)
{
    __shared__ __align__(16) u16 As[128 * 64];
    __shared__ __align__(16) u16 Bs[128 * 64];
    f32x4 acc[4][4];
    gemm128_core(A, W, blockIdx.y * 128, blockIdx.x * 128, As, Bs, acc);

    const int tid = threadIdx.x, w = tid >> 6, l = tid & 63;
    const int lr = l & 15, lq = l >> 4;
    const int r0 = blockIdx.y * 128 + (w >> 1) * 64;
    const int c0 = blockIdx.x * 128 + (w & 1) * 64;
#pragma unroll
    for (int i = 0; i < 4; ++i)
#pragma unroll
        for (int j = 0; j < 4; ++j)
#pragma unroll
            for (int r = 0; r < 4; ++r)
                out[(size_t)(r0 + i * 16 + lq * 4 + r) * 1024 + (c0 + j * 16 + lr)] = acc[i][j][r];
}

extern "C" void kernel_launch(void* const* d_in, const int* in_sizes, int n_in,
                              void* d_out, int out_size, void* d_ws, size_t ws_size,
                              hipStream_t stream)
{
    const float* q  = (const float*)d_in[0];
    const float* k  = (const float*)d_in[1];
    const float* v  = (const float*)d_in[2];
    const float* Wq = (const float*)d_in[3];
    const float* Wk = (const float*)d_in[4];
    const float* Wv = (const float*)d_in[5];
    const float* Wo = (const float*)d_in[6];

    // workspace layout (u16 elements); needs 58,720,256 bytes.
    u16* ws   = (u16*)d_ws;
    u16* Xq   = ws;              // 4M elems
    u16* Xk   = ws + 4194304;
    u16* Xv   = ws + 8388608;
    u16* Wqb  = ws + 12582912;   // 1M each
    u16* Wkb  = ws + 13631488;
    u16* Wvb  = ws + 14680064;
    u16* Wob  = ws + 15728640;
    u16* Qb   = ws + 16777216;   // 4M each
    u16* Kb   = ws + 20971520;
    u16* Vtmp = ws + 25165824;
    u16* Vt   = Xq;   // alias: Xq dead after proj_gemm
    u16* At   = Xk;   // alias: Xk dead after proj_gemm

    convert_all<<<dim3(512, 1, 7), 256, 0, stream>>>(q, k, v, Wq, Wk, Wv, Wo,
                                                     Xq, Xk, Xv, Wqb, Wkb, Wvb, Wob);
    proj_gemm<<<dim3(8, 32, 3), 256, 0, stream>>>(Xq, Xk, Xv, Wqb, Wkb, Wvb, Qb, Kb, Vtmp);
    transpose_v<<<dim3(32, 32), 256, 0, stream>>>(Vtmp, Vt);
    attn_kernel<<<dim3(32, 32), 128, 0, stream>>>(Qb, Kb, Vt, At);
    out_gemm<<<dim3(8, 32), 256, 0, stream>>>(At, Wob, (float*)d_out);
}

// Round 8
// 227.171 us; speedup vs baseline: 1.0379x; 1.0379x over previous
//
#include <hip/hip_runtime.h>
#include <hip/hip_bf16.h>

#define DEV __device__ __forceinline__

typedef __bf16 bf16x8 __attribute__((ext_vector_type(8)));
typedef float  f32x4  __attribute__((ext_vector_type(4)));
typedef unsigned short u16;

static constexpr float LOG2E = 1.44269504088896340736f;

// fp32 -> bf16 round-to-nearest-even (scalar)
DEV u16 f2bf(float f) {
    unsigned u = __float_as_uint(f);
    u += 0x7fffu + ((u >> 16) & 1u);
    return (u16)(u >> 16);
}

// pack 2 fp32 -> 2 bf16 in one v_perm (round-half-up)
DEV unsigned pack_rn(float a, float b) {
    unsigned ua = __float_as_uint(a) + 0x8000u;
    unsigned ub = __float_as_uint(b) + 0x8000u;
    return __builtin_amdgcn_perm(ub, ua, 0x07060302u);  // [ub.hi16 : ua.hi16]
}

typedef const __attribute__((address_space(1))) void* gas_ptr;
typedef __attribute__((address_space(3))) void* las_ptr;

// async global->LDS, 16B per lane. LDS dest = wave-uniform base + lane*16.
DEV void async16(const void* g, void* l) {
    __builtin_amdgcn_global_load_lds((gas_ptr)g, (las_ptr)l, 16, 0, 0);
}

// ---------------- convert fp32 -> bf16 (7 tensors via blockIdx.z) -------------
__global__ __launch_bounds__(256)
void convert_all(const float* q, const float* k, const float* v,
                 const float* wq, const float* wk, const float* wv, const float* wo,
                 u16* oq, u16* ok, u16* ov, u16* owq, u16* owk, u16* owv, u16* owo)
{
    const float* src; u16* dst; int n;
    switch (blockIdx.z) {
        case 0: src = q;  dst = oq;  n = 4194304; break;
        case 1: src = k;  dst = ok;  n = 4194304; break;
        case 2: src = v;  dst = ov;  n = 4194304; break;
        case 3: src = wq; dst = owq; n = 1048576; break;
        case 4: src = wk; dst = owk; n = 1048576; break;
        case 5: src = wv; dst = owv; n = 1048576; break;
        default: src = wo; dst = owo; n = 1048576; break;
    }
    int n4 = n >> 2;
    int stride = gridDim.x * blockDim.x;
    for (int i = blockIdx.x * blockDim.x + threadIdx.x; i < n4; i += stride) {
        float4 f = ((const float4*)src)[i];
        uint2 o;
        o.x = pack_rn(f.x, f.y);
        o.y = pack_rn(f.z, f.w);
        ((uint2*)dst)[i] = o;
    }
}

// ------------- 128x128 bf16 GEMM core: C = A[rows,1024] @ B[rows,1024]^T ------
// 256 threads = 4 waves in 2x2; each wave computes 64x64 (4x4 mfma tiles).
// LDS tiles XOR-swizzled (16B chunk ^= row&7) -> conflict-floor b128 reads.
DEV void gemm128_core(const u16* __restrict__ A, const u16* __restrict__ B,
                      int rowBase, int colBase,
                      u16* As, u16* Bs, f32x4 acc[4][4])
{
    const int tid = threadIdx.x;
    const int w = tid >> 6, l = tid & 63;
    const int lr = l & 15, lq = l >> 4;
    const int srow = l >> 3, swcol = ((l & 7) ^ (l >> 3)) * 8;
    const int wr0 = (w >> 1) * 64, wc0 = (w & 1) * 64;
    const int sx = lr & 7;

#pragma unroll
    for (int i = 0; i < 4; ++i)
#pragma unroll
        for (int j = 0; j < 4; ++j) acc[i][j] = (f32x4){0.f, 0.f, 0.f, 0.f};

    for (int k0 = 0; k0 < 1024; k0 += 64) {
        __syncthreads();   // previous iter's LDS reads done
#pragma unroll
        for (int c = 0; c < 4; ++c) {
            const int ci = c * 4 + w;            // 1KB chunk = 8 rows of 128B
            const int row = ci * 8 + srow;
            async16(&A[(size_t)(rowBase + row) * 1024 + k0 + swcol], &As[ci * 512]);
            async16(&B[(size_t)(colBase + row) * 1024 + k0 + swcol], &Bs[ci * 512]);
        }
        __syncthreads();   // vmcnt(0) drain makes staging visible
#pragma unroll
        for (int ks = 0; ks < 2; ++ks) {
            bf16x8 a[4], b[4];
#pragma unroll
            for (int i = 0; i < 4; ++i)
                a[i] = *(const bf16x8*)&As[(wr0 + i * 16 + lr) * 64 + (((ks * 4 + lq) ^ sx) * 8)];
#pragma unroll
            for (int j = 0; j < 4; ++j)
                b[j] = *(const bf16x8*)&Bs[(wc0 + j * 16 + lr) * 64 + (((ks * 4 + lq) ^ sx) * 8)];
#pragma unroll
            for (int i = 0; i < 4; ++i)
#pragma unroll
                for (int j = 0; j < 4; ++j)
                    acc[i][j] = __builtin_amdgcn_mfma_f32_16x16x32_bf16(a[i], b[j], acc[i][j], 0, 0, 0);
        }
    }
}

// --------- QKV projection: X[4096,1024] @ W^T -> [B,H,S,D] bf16 ---------------
// Q output (z==0) pre-scaled by LOG2E so attention softmax is a raw exp2.
__global__ __launch_bounds__(256, 4)
void proj_gemm(const u16* __restrict__ Xq, const u16* __restrict__ Xk, const u16* __restrict__ Xv,
               const u16* __restrict__ Wq, const u16* __restrict__ Wk, const u16* __restrict__ Wv,
               u16* __restrict__ Qo, u16* __restrict__ Ko, u16* __restrict__ Vo)
{
    __shared__ __align__(16) u16 As[128 * 64];
    __shared__ __align__(16) u16 Bs[128 * 64];
    const u16* A; const u16* W; u16* C; float scale;
    if (blockIdx.z == 0)      { A = Xq; W = Wq; C = Qo; scale = LOG2E; }
    else if (blockIdx.z == 1) { A = Xk; W = Wk; C = Ko; scale = 1.0f; }
    else                      { A = Xv; W = Wv; C = Vo; scale = 1.0f; }

    f32x4 acc[4][4];
    gemm128_core(A, W, blockIdx.y * 128, blockIdx.x * 128, As, Bs, acc);

    const int tid = threadIdx.x, w = tid >> 6, l = tid & 63;
    const int lr = l & 15, lq = l >> 4;
    const int r0 = blockIdx.y * 128 + (w >> 1) * 64;
    const int c0 = blockIdx.x * 128 + (w & 1) * 64;
#pragma unroll
    for (int i = 0; i < 4; ++i)
#pragma unroll
        for (int j = 0; j < 4; ++j)
#pragma unroll
            for (int r = 0; r < 4; ++r) {
                int row = r0 + i * 16 + lq * 4 + r;   // X row = s*2 + b
                int col = c0 + j * 16 + lr;           // n = h*64 + d
                int s = row >> 1, b = row & 1, h = col >> 6, d = col & 63;
                C[(size_t)((b * 16 + h) * 2048 + s) * 64 + d] = f2bf(acc[i][j][r] * scale);
            }
}

// --------- V transpose: [B,H,S,D] -> [B,H,D,S] bf16 ---------------------------
__global__ __launch_bounds__(256)
void transpose_v(const u16* __restrict__ Vin, u16* __restrict__ Vout)
{
    __shared__ u16 T[64][72];
    const int bh = blockIdx.y;
    const int s0 = blockIdx.x * 64;
    const int t = threadIdx.x;
    const size_t base = (size_t)bh * 2048 * 64;
    const int row = t >> 3, cc = (t & 7) * 8;
#pragma unroll
    for (int i = 0; i < 2; ++i) {
        int r = i * 32 + row;
        uint4 v = *(const uint4*)&Vin[base + (size_t)(s0 + r) * 64 + cc];
        u16* p = (u16*)&v;
#pragma unroll
        for (int j = 0; j < 8; ++j) T[r][cc + j] = p[j];
    }
    __syncthreads();
#pragma unroll
    for (int i = 0; i < 2; ++i) {
        int d = i * 32 + row;
        alignas(16) u16 tmp[8];
#pragma unroll
        for (int j = 0; j < 8; ++j) tmp[j] = T[cc + j][d];
        *(uint4*)&Vout[base + (size_t)d * 2048 + s0 + cc] = *(const uint4*)tmp;
    }
}

// --------- flash attention v6 (best measured: 63.6us): Q-tile 64, 4 blk/CU ----
__global__ __launch_bounds__(256, 4)
void attn_kernel(const u16* __restrict__ Qg, const u16* __restrict__ Kg,
                 const u16* __restrict__ Vtg, u16* __restrict__ attn)
{
    __shared__ __align__(16) u16 KV[2][8192];      // [buf][ K tile 8KB | V tile 8KB ]
    __shared__ __align__(16) u16 Ps[4 * 1024];     // per-wave P [16][64], swizzled

    const int tid = threadIdx.x, w = tid >> 6, l = tid & 63;
    const int lr = l & 15, lq = l >> 4;
    const int sx = lr & 7;
    // XCD-aware remap: xcd = lin&7; 4 bh per xcd, 32 q-blocks per bh
    const int lin = blockIdx.x + (blockIdx.y << 5);   // gridDim.x == 32
    const int grp = lin >> 3;                          // [0,128)
    const int bh = (lin & 7) * 4 + (grp >> 5);
    const int q0 = (grp & 31) * 64;
    const size_t base = (size_t)bh * 2048 * 64;
    const int srow = l >> 3, swcol = ((l & 7) ^ (l >> 3)) * 8;
    u16* Pw = &Ps[w * 1024];                          // this wave's P [16][64]

    // stage Q tile (64x64 = 8KB) into KV[1][0..4096); K0/V0 into KV[0]
#pragma unroll
    for (int c = 0; c < 2; ++c) {
        int ci = w * 2 + c;
        int row = ci * 8 + srow;
        async16(&Qg[base + (size_t)(q0 + row) * 64 + swcol], &KV[1][ci * 512]);
        async16(&Kg[base + (size_t)row * 64 + swcol], &KV[0][ci * 512]);
        async16(&Vtg[base + (size_t)row * 2048 + swcol], &KV[0][4096 + ci * 512]);
    }
    __syncthreads();   // staging visible

    // hoist Q fragments to registers (KV[1] then becomes the second K/V buffer)
    bf16x8 bq[2];
#pragma unroll
    for (int ks = 0; ks < 2; ++ks)
        bq[ks] = *(const bf16x8*)&KV[1][(w * 16 + lr) * 64 + (((ks * 4 + lq) ^ sx) * 8)];
    __syncthreads();   // all waves done reading Q before buf1 is overwritten

    f32x4 O[4];            // O^T: [d-tile mt][q=lane&15]; d = mt*16+lq*4+r
    float l_i = 0.f;
#pragma unroll
    for (int mt = 0; mt < 4; ++mt) O[mt] = (f32x4){0.f, 0.f, 0.f, 0.f};

    for (int kt = 0; kt < 32; ++kt) {
        const int cur = kt & 1;
        const u16* Ks = &KV[cur][0];
        const u16* Vs = &KV[cur][4096];
        // prefetch next K/V tile into the alternate buffer (overlaps compute)
        if (kt < 31) {
#pragma unroll
            for (int c = 0; c < 2; ++c) {
                int ci = w * 2 + c;
                int row = ci * 8 + srow;
                async16(&Kg[base + (size_t)((kt + 1) * 64 + row) * 64 + swcol], &KV[cur ^ 1][ci * 512]);
                async16(&Vtg[base + (size_t)row * 2048 + (kt + 1) * 64 + swcol], &KV[cur ^ 1][4096 + ci * 512]);
            }
        }

        // S^T = K_tile * Q_tile^T : D[m=k_idx][n=q]; q = lane&15, k = mt*16+lq*4+r
        f32x4 S[4];
        {
            bf16x8 ak0[4], ak1[4];
#pragma unroll
            for (int mt = 0; mt < 4; ++mt)
                ak0[mt] = *(const bf16x8*)&Ks[(mt * 16 + lr) * 64 + ((lq ^ sx) * 8)];
#pragma unroll
            for (int mt = 0; mt < 4; ++mt)
                ak1[mt] = *(const bf16x8*)&Ks[(mt * 16 + lr) * 64 + (((4 + lq) ^ sx) * 8)];
#pragma unroll
            for (int mt = 0; mt < 4; ++mt) {
                S[mt] = __builtin_amdgcn_mfma_f32_16x16x32_bf16(ak0[mt], bq[0],
                                (f32x4){0.f, 0.f, 0.f, 0.f}, 0, 0, 0);
                S[mt] = __builtin_amdgcn_mfma_f32_16x16x32_bf16(ak1[mt], bq[1], S[mt], 0, 0, 0);
            }
        }

        // softmax (no max subtraction; Q pre-scaled by LOG2E so raw exp2):
        {
            float rs = 0.f;
#pragma unroll
            for (int mt = 0; mt < 4; ++mt)
#pragma unroll
                for (int r = 0; r < 4; ++r) {
                    float p = __builtin_amdgcn_exp2f(S[mt][r]);
                    S[mt][r] = p;
                    rs += p;
                }
            rs += __shfl_xor(rs, 16, 64);
            rs += __shfl_xor(rs, 32, 64);
            l_i += rs;
            // P[q][k]: q = lr, k = mt*16+lq*4+r; chunk = (k>>3)^(q&7)
#pragma unroll
            for (int mt = 0; mt < 4; ++mt) {
                uint2 pk;
                pk.x = pack_rn(S[mt][0], S[mt][1]);
                pk.y = pack_rn(S[mt][2], S[mt][3]);
                *(uint2*)&Pw[lr * 64 + (((mt * 2 + (lq >> 1)) ^ sx) * 8) + (lq & 1) * 4] = pk;
            }
        }
        // same-wave LDS write->read: wave-ordered, no barrier needed

        // O^T += V^T * P^T : mfma(A = Vs rows (d), B = Pw rows (q))
#pragma unroll
        for (int ks = 0; ks < 2; ++ks) {
            bf16x8 av[4];
            bf16x8 bp = *(const bf16x8*)&Pw[lr * 64 + (((ks * 4 + lq) ^ sx) * 8)];
#pragma unroll
            for (int mt = 0; mt < 4; ++mt)
                av[mt] = *(const bf16x8*)&Vs[(mt * 16 + lr) * 64 + (((ks * 4 + lq) ^ sx) * 8)];
#pragma unroll
            for (int mt = 0; mt < 4; ++mt)
                O[mt] = __builtin_amdgcn_mfma_f32_16x16x32_bf16(av[mt], bp, O[mt], 0, 0, 0);
        }

        __syncthreads();   // next-tile staging done; everyone done reading cur
    }

    // epilogue: lane holds q = lr -> s = q0 + w*16 + lr; d = mt*16+lq*4+r
    const int b = bh >> 4, h = bh & 15;
    const int s = q0 + w * 16 + lr;
    const float inv = 1.f / l_i;
    u16* orow = &attn[(size_t)(s * 2 + b) * 1024 + h * 64];
#pragma unroll
    for (int mt = 0; mt < 4; ++mt) {
        uint2 pk;
        pk.x = pack_rn(O[mt][0] * inv, O[mt][1] * inv);
        pk.y = pack_rn(O[mt][2] * inv, O[mt][3] * inv);
        *(uint2*)&orow[mt * 16 + lq * 4] = pk;
    }
}

// --------- output projection: attn[4096,1024] @ Wo^T -> fp32 out --------------
// 128x64 tile, 2 waves (w0 rows 0-63, w1 rows 64-127, each 64x64 with 4x4
// mfma tiles -> same MFMA:LDS ratio as the 128x128 core). Grid 512 blocks
// = 2 blocks/CU (vs 1 for 128x128) so one block's compute hides the other's
// barrier drain. LDS 24KB.
__global__ __launch_bounds__(128)
void out_gemm(const u16* __restrict__ A, const u16* __restrict__ W, float* __restrict__ out)
{
    __shared__ __align__(16) u16 As[128 * 64];   // 16KB
    __shared__ __align__(16) u16 Bs[64 * 64];    // 8KB
    const int tid = threadIdx.x;
    const int w = tid >> 6, l = tid & 63;
    const int lr = l & 15, lq = l >> 4;
    const int srow = l >> 3, swcol = ((l & 7) ^ (l >> 3)) * 8;
    const int sx = lr & 7;
    const int rowBase = blockIdx.y * 128;
    const int colBase = blockIdx.x * 64;

    f32x4 acc[4][4];
#pragma unroll
    for (int i = 0; i < 4; ++i)
#pragma unroll
        for (int j = 0; j < 4; ++j) acc[i][j] = (f32x4){0.f, 0.f, 0.f, 0.f};

    for (int k0 = 0; k0 < 1024; k0 += 64) {
        __syncthreads();
#pragma unroll
        for (int c = 0; c < 8; ++c) {            // A: 16 chunks, 8 per wave
            const int ci = w * 8 + c;
            const int row = ci * 8 + srow;
            async16(&A[(size_t)(rowBase + row) * 1024 + k0 + swcol], &As[ci * 512]);
        }
#pragma unroll
        for (int c = 0; c < 4; ++c) {            // B: 8 chunks, 4 per wave
            const int ci = w * 4 + c;
            const int row = ci * 8 + srow;
            async16(&W[(size_t)(colBase + row) * 1024 + k0 + swcol], &Bs[ci * 512]);
        }
        __syncthreads();
#pragma unroll
        for (int ks = 0; ks < 2; ++ks) {
            bf16x8 a[4], b[4];
#pragma unroll
            for (int i = 0; i < 4; ++i)
                a[i] = *(const bf16x8*)&As[(w * 64 + i * 16 + lr) * 64 + (((ks * 4 + lq) ^ sx) * 8)];
#pragma unroll
            for (int j = 0; j < 4; ++j)
                b[j] = *(const bf16x8*)&Bs[(j * 16 + lr) * 64 + (((ks * 4 + lq) ^ sx) * 8)];
#pragma unroll
            for (int i = 0; i < 4; ++i)
#pragma unroll
                for (int j = 0; j < 4; ++j)
                    acc[i][j] = __builtin_amdgcn_mfma_f32_16x16x32_bf16(a[i], b[j], acc[i][j], 0, 0, 0);
        }
    }

    const int r0 = rowBase + w * 64;
#pragma unroll
    for (int i = 0; i < 4; ++i)
#pragma unroll
        for (int j = 0; j < 4; ++j)
#pragma unroll
            for (int r = 0; r < 4; ++r)
                out[(size_t)(r0 + i * 16 + lq * 4 + r) * 1024 + (colBase + j * 16 + lr)] = acc[i][j][r];
}

extern "C" void kernel_launch(void* const* d_in, const int* in_sizes, int n_in,
                              void* d_out, int out_size, void* d_ws, size_t ws_size,
                              hipStream_t stream)
{
    const float* q  = (const float*)d_in[0];
    const float* k  = (const float*)d_in[1];
    const float* v  = (const float*)d_in[2];
    const float* Wq = (const float*)d_in[3];
    const float* Wk = (const float*)d_in[4];
    const float* Wv = (const float*)d_in[5];
    const float* Wo = (const float*)d_in[6];

    // workspace layout (u16 elements); needs 58,720,256 bytes.
    u16* ws   = (u16*)d_ws;
    u16* Xq   = ws;              // 4M elems
    u16* Xk   = ws + 4194304;
    u16* Xv   = ws + 8388608;
    u16* Wqb  = ws + 12582912;   // 1M each
    u16* Wkb  = ws + 13631488;
    u16* Wvb  = ws + 14680064;
    u16* Wob  = ws + 15728640;
    u16* Qb   = ws + 16777216;   // 4M each
    u16* Kb   = ws + 20971520;
    u16* Vtmp = ws + 25165824;
    u16* Vt   = Xq;   // alias: Xq dead after proj_gemm
    u16* At   = Xk;   // alias: Xk dead after proj_gemm

    convert_all<<<dim3(512, 1, 7), 256, 0, stream>>>(q, k, v, Wq, Wk, Wv, Wo,
                                                     Xq, Xk, Xv, Wqb, Wkb, Wvb, Wob);
    proj_gemm<<<dim3(8, 32, 3), 256, 0, stream>>>(Xq, Xk, Xv, Wqb, Wkb, Wvb, Qb, Kb, Vtmp);
    transpose_v<<<dim3(32, 32), 256, 0, stream>>>(Vtmp, Vt);
    attn_kernel<<<dim3(32, 32), 256, 0, stream>>>(Qb, Kb, Vt, At);
    out_gemm<<<dim3(16, 32), 128, 0, stream>>>(At, Wob, (float*)d_out);
}